// Round 7
// baseline (49.170 us; speedup 1.0000x reference)
//
#include <hip/hip_runtime.h>

#define NROWS 4096
#define NCOLS 10000
#define NLAT  64
#define NCOLG 2500              /* NCOLS / 4 */
#define TPB   256
#define NBX   10                /* column blocks in K1 */
#define NRC   256               /* row chunks: 10*256 = 2560 blocks = 10/CU */
#define RPC   16                /* rows per chunk */
#define HPC   8                 /* rows per chain (2 chains/thread) */
#define NCB   40                /* column blocks in fold */
#define CPB   250               /* columns per fold block */
#define NSLICE 32               /* chunk slices in fold */
#define CPS   (NRC / NSLICE)    /* 8 chunks per slice */
#define NBLK2 (NCB * NSLICE)    /* 1280 fold blocks = 5/CU */

// K1: pure streaming pass over X (163.84 MB). Thread owns 4 consecutive
// columns (float4, 1024B/wave); TWO independent 8-row load chains per thread
// for deeper MLP; 2560 blocks = 10/CU exact. Partial colsum/colsum^2 to
// fixed slots -> deterministic.
__global__ __launch_bounds__(TPB) void colsum_partials(
        const float* __restrict__ X,
        float* __restrict__ ps, float* __restrict__ ps2) {
    int jg = blockIdx.x * TPB + threadIdx.x;          // column group
    if (jg >= NCOLG) return;
    const float* pa = X + (size_t)blockIdx.y * RPC * NCOLS + (size_t)jg * 4;
    const float* pb = pa + (size_t)HPC * NCOLS;
    float as0=0.f,as1=0.f,as2=0.f,as3=0.f,aq0=0.f,aq1=0.f,aq2=0.f,aq3=0.f;
    float bs0=0.f,bs1=0.f,bs2=0.f,bs3=0.f,bq0=0.f,bq1=0.f,bq2=0.f,bq3=0.f;
    #pragma unroll
    for (int r = 0; r < HPC; ++r) {
        float4 a = *reinterpret_cast<const float4*>(pa);
        float4 b = *reinterpret_cast<const float4*>(pb);
        pa += NCOLS; pb += NCOLS;
        as0 += a.x; as1 += a.y; as2 += a.z; as3 += a.w;
        aq0 = fmaf(a.x, a.x, aq0); aq1 = fmaf(a.y, a.y, aq1);
        aq2 = fmaf(a.z, a.z, aq2); aq3 = fmaf(a.w, a.w, aq3);
        bs0 += b.x; bs1 += b.y; bs2 += b.z; bs3 += b.w;
        bq0 = fmaf(b.x, b.x, bq0); bq1 = fmaf(b.y, b.y, bq1);
        bq2 = fmaf(b.z, b.z, bq2); bq3 = fmaf(b.w, b.w, bq3);
    }
    size_t o = (size_t)blockIdx.y * NCOLS + (size_t)jg * 4;
    *reinterpret_cast<float4*>(ps  + o) =
        make_float4(as0 + bs0, as1 + bs1, as2 + bs2, as3 + bs3);
    *reinterpret_cast<float4*>(ps2 + o) =
        make_float4(aq0 + bq0, aq1 + bq1, aq2 + bq2, aq3 + bq3);
}

// K2: fold 8 chunks + one coalesced V sweep -> t[64]-partial + q-partial per
// block, TRANSPOSED output tpT[f][bid] (row 64 = q). Lane = latent f; V reads
// 256B/wave coalesced; lds_s[c] wave-uniform broadcast. Fixed order.
__global__ __launch_bounds__(TPB) void fold_qt(
        const float* __restrict__ ps, const float* __restrict__ ps2,
        const float* __restrict__ V, float* __restrict__ tpT) {
    const int cb = blockIdx.x;          // 0..39
    const int sl = blockIdx.y;          // 0..31
    const int tid = threadIdx.x;
    __shared__ float lds_s[CPB], lds_s2[CPB];
    if (tid < CPB) {
        const int col = cb * CPB + tid;
        float s = 0.f, s2 = 0.f;
        const int c0 = sl * CPS;
        #pragma unroll
        for (int c = c0; c < c0 + CPS; ++c) {        // coalesced 1KB runs
            s  += ps [(size_t)c * NCOLS + col];
            s2 += ps2[(size_t)c * NCOLS + col];
        }
        lds_s[tid] = s; lds_s2[tid] = s2;
    }
    __syncthreads();

    const int lane = tid & 63, w = tid >> 6;
    float at = 0.f, aq = 0.f;
    const float* Vb = V + (size_t)cb * CPB * NLAT;
    #pragma unroll 4
    for (int c = w; c < CPB; c += 4) {
        float v = Vb[(size_t)c * NLAT + lane];       // 256B/wave, L2-hit
        at = fmaf(lds_s[c], v, at);
        aq = fmaf(lds_s2[c], v * v, aq);
    }
    #pragma unroll
    for (int st = 1; st < 64; st <<= 1) aq += __shfl_xor(aq, st, 64);

    __shared__ float lt[4][NLAT];
    __shared__ float lq[4];
    lt[w][lane] = at;
    if (lane == 0) lq[w] = aq;
    __syncthreads();

    const int bid = sl * NCB + cb;                   // 0..1279
    if (tid < NLAT)
        tpT[(size_t)tid * NBLK2 + bid] = lt[0][tid] + lt[1][tid]
                                       + lt[2][tid] + lt[3][tid];
    if (tid == 0)
        tpT[(size_t)NLAT * NBLK2 + bid] = lq[0] + lq[1] + lq[2] + lq[3];
}

// K3: out = 0.5*(sum_f t[f]^2 - q). 16 waves; wave w reduces contiguous
// 5.12KB rows r = w, w+16, ... (coalesced 256B steps + butterfly).
__global__ __launch_bounds__(1024) void finalize(
        const float* __restrict__ tpT, float* __restrict__ out) {
    const int tid = threadIdx.x, lane = tid & 63, w = tid >> 6;
    __shared__ float red[NLAT + 1];
    for (int r = w; r < NLAT + 1; r += 16) {
        const float* row = tpT + (size_t)r * NBLK2;
        float a = 0.f;
        #pragma unroll
        for (int i = 0; i < NBLK2 / 64; ++i) a += row[i * 64 + lane];
        #pragma unroll
        for (int st = 1; st < 64; st <<= 1) a += __shfl_xor(a, st, 64);
        if (lane == 0) red[r] = a;
    }
    __syncthreads();
    if (w == 0) {
        float t = red[lane];
        float d = t * t;
        #pragma unroll
        for (int st = 1; st < 64; st <<= 1) d += __shfl_xor(d, st, 64);
        if (lane == 0) out[0] = 0.5f * (d - red[NLAT]);
    }
}

extern "C" void kernel_launch(void* const* d_in, const int* in_sizes, int n_in,
                              void* d_out, int out_size, void* d_ws, size_t ws_size,
                              hipStream_t stream) {
    const float* X = (const float*)d_in[0];   // [4096, 10000] f32
    const float* V = (const float*)d_in[1];   // [10000, 64]  f32
    float* out = (float*)d_out;               // scalar f32

    float* ps  = (float*)d_ws;                         // [NRC][NCOLS]
    float* ps2 = ps  + (size_t)NRC * NCOLS;            // [NRC][NCOLS]
    float* tpT = ps2 + (size_t)NRC * NCOLS;            // [NLAT+1][NBLK2]

    colsum_partials<<<dim3(NBX, NRC), TPB, 0, stream>>>(X, ps, ps2);
    fold_qt<<<dim3(NCB, NSLICE), TPB, 0, stream>>>(ps, ps2, V, tpT);
    finalize<<<1, 1024, 0, stream>>>(tpT, out);
}

// Round 8
// 43.768 us; speedup vs baseline: 1.1234x; 1.1234x over previous
//
#include <hip/hip_runtime.h>

#define NROWS 4096
#define NCOLS 10000
#define NLAT  64
#define NCOLG 2500              /* NCOLS / 4 */
#define TPB   256
#define NBX   10                /* column blocks in K1 */
#define NRC   128               /* row chunks: 10*128 = 1280 blocks = 5/CU */
#define RPC   32                /* rows per chunk */
#define HPC   16                /* rows per chain (2 independent chains) */
#define NCB   40                /* column blocks in fold */
#define CPB   250               /* columns per fold block */
#define NSLICE 16               /* chunk slices in fold */
#define CPS   (NRC / NSLICE)    /* 8 chunks per slice */
#define NBLK2 (NCB * NSLICE)    /* 640 fold blocks */

// K1: pure streaming pass over X (163.84 MB). Thread owns 4 consecutive
// columns (float4, 1024B/wave coalesced). TWO independent 16-row load
// chains (the ONLY change vs the 42.8us R6 kernel) to double outstanding
// loads at 5 blocks/CU = 20 waves/CU (<=32 cap). Fixed slots, deterministic.
__global__ __launch_bounds__(TPB) void colsum_partials(
        const float* __restrict__ X,
        float* __restrict__ ps, float* __restrict__ ps2) {
    int jg = blockIdx.x * TPB + threadIdx.x;          // column group
    if (jg >= NCOLG) return;
    const float* pa = X + (size_t)blockIdx.y * RPC * NCOLS + (size_t)jg * 4;
    const float* pb = pa + (size_t)HPC * NCOLS;
    float as0=0.f,as1=0.f,as2=0.f,as3=0.f,aq0=0.f,aq1=0.f,aq2=0.f,aq3=0.f;
    float bs0=0.f,bs1=0.f,bs2=0.f,bs3=0.f,bq0=0.f,bq1=0.f,bq2=0.f,bq3=0.f;
    #pragma unroll 8
    for (int r = 0; r < HPC; ++r) {
        float4 a = *reinterpret_cast<const float4*>(pa);
        float4 b = *reinterpret_cast<const float4*>(pb);
        pa += NCOLS; pb += NCOLS;
        as0 += a.x; as1 += a.y; as2 += a.z; as3 += a.w;
        aq0 = fmaf(a.x, a.x, aq0); aq1 = fmaf(a.y, a.y, aq1);
        aq2 = fmaf(a.z, a.z, aq2); aq3 = fmaf(a.w, a.w, aq3);
        bs0 += b.x; bs1 += b.y; bs2 += b.z; bs3 += b.w;
        bq0 = fmaf(b.x, b.x, bq0); bq1 = fmaf(b.y, b.y, bq1);
        bq2 = fmaf(b.z, b.z, bq2); bq3 = fmaf(b.w, b.w, bq3);
    }
    size_t o = (size_t)blockIdx.y * NCOLS + (size_t)jg * 4;
    *reinterpret_cast<float4*>(ps  + o) =
        make_float4(as0 + bs0, as1 + bs1, as2 + bs2, as3 + bs3);
    *reinterpret_cast<float4*>(ps2 + o) =
        make_float4(aq0 + bq0, aq1 + bq1, aq2 + bq2, aq3 + bq3);
}

// K2: fold 8 chunks + one coalesced V sweep -> t[64]-partial + q-partial per
// block, TRANSPOSED output tpT[f][bid] (row 64 = q). Identical to R6.
__global__ __launch_bounds__(TPB) void fold_qt(
        const float* __restrict__ ps, const float* __restrict__ ps2,
        const float* __restrict__ V, float* __restrict__ tpT) {
    const int cb = blockIdx.x;          // 0..39
    const int sl = blockIdx.y;          // 0..15
    const int tid = threadIdx.x;
    __shared__ float lds_s[CPB], lds_s2[CPB];
    if (tid < CPB) {
        const int col = cb * CPB + tid;
        float s = 0.f, s2 = 0.f;
        const int c0 = sl * CPS;
        #pragma unroll
        for (int c = c0; c < c0 + CPS; ++c) {        // coalesced 1KB runs
            s  += ps [(size_t)c * NCOLS + col];
            s2 += ps2[(size_t)c * NCOLS + col];
        }
        lds_s[tid] = s; lds_s2[tid] = s2;
    }
    __syncthreads();

    const int lane = tid & 63, w = tid >> 6;
    float at = 0.f, aq = 0.f;
    const float* Vb = V + (size_t)cb * CPB * NLAT;
    #pragma unroll 4
    for (int c = w; c < CPB; c += 4) {
        float v = Vb[(size_t)c * NLAT + lane];       // 256B/wave, L2-hit
        at = fmaf(lds_s[c], v, at);
        aq = fmaf(lds_s2[c], v * v, aq);
    }
    #pragma unroll
    for (int st = 1; st < 64; st <<= 1) aq += __shfl_xor(aq, st, 64);

    __shared__ float lt[4][NLAT];
    __shared__ float lq[4];
    lt[w][lane] = at;
    if (lane == 0) lq[w] = aq;
    __syncthreads();

    const int bid = sl * NCB + cb;                   // 0..639
    if (tid < NLAT)
        tpT[(size_t)tid * NBLK2 + bid] = lt[0][tid] + lt[1][tid]
                                       + lt[2][tid] + lt[3][tid];
    if (tid == 0)
        tpT[(size_t)NLAT * NBLK2 + bid] = lq[0] + lq[1] + lq[2] + lq[3];
}

// K3: out = 0.5*(sum_f t[f]^2 - q). Identical to R6.
__global__ __launch_bounds__(1024) void finalize(
        const float* __restrict__ tpT, float* __restrict__ out) {
    const int tid = threadIdx.x, lane = tid & 63, w = tid >> 6;
    __shared__ float red[NLAT + 1];
    for (int r = w; r < NLAT + 1; r += 16) {
        const float* row = tpT + (size_t)r * NBLK2;
        float a = 0.f;
        #pragma unroll
        for (int i = 0; i < NBLK2 / 64; ++i) a += row[i * 64 + lane];
        #pragma unroll
        for (int st = 1; st < 64; st <<= 1) a += __shfl_xor(a, st, 64);
        if (lane == 0) red[r] = a;
    }
    __syncthreads();
    if (w == 0) {
        float t = red[lane];
        float d = t * t;
        #pragma unroll
        for (int st = 1; st < 64; st <<= 1) d += __shfl_xor(d, st, 64);
        if (lane == 0) out[0] = 0.5f * (d - red[NLAT]);
    }
}

extern "C" void kernel_launch(void* const* d_in, const int* in_sizes, int n_in,
                              void* d_out, int out_size, void* d_ws, size_t ws_size,
                              hipStream_t stream) {
    const float* X = (const float*)d_in[0];   // [4096, 10000] f32
    const float* V = (const float*)d_in[1];   // [10000, 64]  f32
    float* out = (float*)d_out;               // scalar f32

    float* ps  = (float*)d_ws;                         // [NRC][NCOLS]
    float* ps2 = ps  + (size_t)NRC * NCOLS;            // [NRC][NCOLS]
    float* tpT = ps2 + (size_t)NRC * NCOLS;            // [NLAT+1][NBLK2]

    colsum_partials<<<dim3(NBX, NRC), TPB, 0, stream>>>(X, ps, ps2);
    fold_qt<<<dim3(NCB, NSLICE), TPB, 0, stream>>>(ps, ps2, V, tpT);
    finalize<<<1, 1024, 0, stream>>>(tpT, out);
}

// Round 9
// 43.010 us; speedup vs baseline: 1.1432x; 1.0176x over previous
//
#include <hip/hip_runtime.h>

#define NROWS 4096
#define NCOLS 10000
#define NLAT  64
#define NCOLG 2500              /* NCOLS / 4 */
#define TPB   256
#define NBX   10                /* column blocks in K1 */
#define NRC   128               /* row chunks: 10*128 = 1280 blocks = 5/CU */
#define RPC   32                /* rows per chunk */
#define NCB   40                /* column blocks in fold */
#define CPB   250               /* columns per fold block */
#define NSLICE 16               /* chunk slices in fold */
#define CPS   (NRC / NSLICE)    /* 8 chunks per slice */
#define NBLK2 (NCB * NSLICE)    /* 640 fold blocks */

// K1: pure streaming pass over X (163.84 MB), nothing else. Thread owns 4
// consecutive columns (float4, 1024B/wave coalesced); block-row y covers 32
// rows; writes partial colsum/colsum^2 to fixed slots. 1280 blocks = 5/CU
// exact (R7 lesson: blocks/CU * waves/block must stay <= 32). Single load
// chain (R8: 2-chain ILP was neutral -> not latency-limited).
__global__ __launch_bounds__(TPB) void colsum_partials(
        const float* __restrict__ X,
        float* __restrict__ ps, float* __restrict__ ps2) {
    int jg = blockIdx.x * TPB + threadIdx.x;          // column group
    if (jg >= NCOLG) return;
    const float* p = X + (size_t)blockIdx.y * RPC * NCOLS + (size_t)jg * 4;
    float s0=0.f,s1=0.f,s2=0.f,s3=0.f,q0=0.f,q1=0.f,q2=0.f,q3=0.f;
    #pragma unroll 8
    for (int r = 0; r < RPC; ++r) {
        float4 v = *reinterpret_cast<const float4*>(p);
        p += NCOLS;
        s0 += v.x; s1 += v.y; s2 += v.z; s3 += v.w;
        q0 = fmaf(v.x, v.x, q0); q1 = fmaf(v.y, v.y, q1);
        q2 = fmaf(v.z, v.z, q2); q3 = fmaf(v.w, v.w, q3);
    }
    size_t o = (size_t)blockIdx.y * NCOLS + (size_t)jg * 4;
    *reinterpret_cast<float4*>(ps  + o) = make_float4(s0, s1, s2, s3);
    *reinterpret_cast<float4*>(ps2 + o) = make_float4(q0, q1, q2, q3);
}

// K2: fold 8 chunks + one coalesced V sweep -> t[64]-partial + q-partial per
// block, TRANSPOSED output tpT[f][bid] (row 64 = q). Lane = latent f; V reads
// 256B/wave coalesced; lds_s[c] wave-uniform broadcast. Fixed order ->
// deterministic. 640 blocks (R2 lesson: the fold must not be wave-starved).
__global__ __launch_bounds__(TPB) void fold_qt(
        const float* __restrict__ ps, const float* __restrict__ ps2,
        const float* __restrict__ V, float* __restrict__ tpT) {
    const int cb = blockIdx.x;          // 0..39
    const int sl = blockIdx.y;          // 0..15
    const int tid = threadIdx.x;
    __shared__ float lds_s[CPB], lds_s2[CPB];
    if (tid < CPB) {
        const int col = cb * CPB + tid;
        float s = 0.f, s2 = 0.f;
        const int c0 = sl * CPS;
        #pragma unroll
        for (int c = c0; c < c0 + CPS; ++c) {        // coalesced 1KB runs
            s  += ps [(size_t)c * NCOLS + col];
            s2 += ps2[(size_t)c * NCOLS + col];
        }
        lds_s[tid] = s; lds_s2[tid] = s2;
    }
    __syncthreads();

    const int lane = tid & 63, w = tid >> 6;
    float at = 0.f, aq = 0.f;
    const float* Vb = V + (size_t)cb * CPB * NLAT;
    #pragma unroll 4
    for (int c = w; c < CPB; c += 4) {
        float v = Vb[(size_t)c * NLAT + lane];       // 256B/wave, L2-hit
        at = fmaf(lds_s[c], v, at);
        aq = fmaf(lds_s2[c], v * v, aq);
    }
    #pragma unroll
    for (int st = 1; st < 64; st <<= 1) aq += __shfl_xor(aq, st, 64);

    __shared__ float lt[4][NLAT];
    __shared__ float lq[4];
    lt[w][lane] = at;
    if (lane == 0) lq[w] = aq;
    __syncthreads();

    const int bid = sl * NCB + cb;                   // 0..639
    if (tid < NLAT)
        tpT[(size_t)tid * NBLK2 + bid] = lt[0][tid] + lt[1][tid]
                                       + lt[2][tid] + lt[3][tid];
    if (tid == 0)
        tpT[(size_t)NLAT * NBLK2 + bid] = lq[0] + lq[1] + lq[2] + lq[3];
}

// K3: out = 0.5*(sum_f t[f]^2 - q). 16 waves; wave w reduces contiguous
// 2.56KB rows r = w, w+16, ... (coalesced 256B steps + butterfly).
// No fences/atomics anywhere (R4 lesson: per-block device-scope fences on
// 8 XCDs cost ~100x a kernel-launch boundary).
__global__ __launch_bounds__(1024) void finalize(
        const float* __restrict__ tpT, float* __restrict__ out) {
    const int tid = threadIdx.x, lane = tid & 63, w = tid >> 6;
    __shared__ float red[NLAT + 1];
    for (int r = w; r < NLAT + 1; r += 16) {
        const float* row = tpT + (size_t)r * NBLK2;
        float a = 0.f;
        #pragma unroll
        for (int i = 0; i < NBLK2 / 64; ++i) a += row[i * 64 + lane];
        #pragma unroll
        for (int st = 1; st < 64; st <<= 1) a += __shfl_xor(a, st, 64);
        if (lane == 0) red[r] = a;
    }
    __syncthreads();
    if (w == 0) {
        float t = red[lane];
        float d = t * t;
        #pragma unroll
        for (int st = 1; st < 64; st <<= 1) d += __shfl_xor(d, st, 64);
        if (lane == 0) out[0] = 0.5f * (d - red[NLAT]);
    }
}

extern "C" void kernel_launch(void* const* d_in, const int* in_sizes, int n_in,
                              void* d_out, int out_size, void* d_ws, size_t ws_size,
                              hipStream_t stream) {
    const float* X = (const float*)d_in[0];   // [4096, 10000] f32
    const float* V = (const float*)d_in[1];   // [10000, 64]  f32
    float* out = (float*)d_out;               // scalar f32

    float* ps  = (float*)d_ws;                         // [NRC][NCOLS]
    float* ps2 = ps  + (size_t)NRC * NCOLS;            // [NRC][NCOLS]
    float* tpT = ps2 + (size_t)NRC * NCOLS;            // [NLAT+1][NBLK2]

    colsum_partials<<<dim3(NBX, NRC), TPB, 0, stream>>>(X, ps, ps2);
    fold_qt<<<dim3(NCB, NSLICE), TPB, 0, stream>>>(ps, ps2, V, tpT);
    finalize<<<1, 1024, 0, stream>>>(tpT, out);
}